// Round 14
// baseline (134.828 us; speedup 1.0000x reference)
//
#include <hip/hip_runtime.h>
#include <hip/hip_bf16.h>
#include <cstdint>
#include <cstddef>

// out = (A2 @ E^T) @ W^T, A2[i,j] = a[i-j] lower-tri Toeplitz,
//   a[d] = (d/4096 + 1e-8)^0.2, a[0] = 1e-8^0.2
// gemm_a: T[i,e] = sum_{j<=i} a[i-j] * E[e,j]  (tri, split-j -> T0 + T1)
// gemm_b: out[i,v] = sum_e T0[i,e]*W[v,e] + sum_e T1[i,e]*W[v,e]
// Round 20: R13 was an infrastructure failure (container died twice, kernel
// never ran). Resubmitting R13 unchanged.
// R12 closed the model: per-dstep cost = LDS bank traffic (~2600 cyc) +
// barrier/drain (~800); MFMA hidden. gemm_b gets the same medicine as
// gemm_a: BK=128 (16->8 steps) with dual-A LDS [128][128] using R12's
// PROVEN staging/swizzle, and W moved OFF LDS into double-buffered VGPR
// fragment sets (wb0/wb1, static indexing) prefetched one full step ahead
// (covers L2 latency -- fixes R9's direct-read failure mechanism).
// gemm_b LDS bytes/step 128->96 KB AND steps halve. gemm_a: R12-verified,
// unchanged. prep: unchanged.

#define L_SER 4096
#define DEMB  1024
#define DV    1024

#define R_STRIDE 4352   // shift-replica stride of reversed a; 16B-aligned; zero-padded tail
#define R_O0     4096

typedef __bf16 bf16_t;
typedef __attribute__((ext_vector_type(8))) __bf16 bf16x8;
typedef __attribute__((ext_vector_type(4))) float f32x4;

// direct global->LDS async copy, 16B per lane (dest = uniform base + lane*16)
__device__ __forceinline__ void glds16(const bf16_t* g, bf16_t* l) {
    __builtin_amdgcn_global_load_lds(
        (const __attribute__((address_space(1))) unsigned int*)(const void*)g,
        (__attribute__((address_space(3))) unsigned int*)(void*)l,
        16, 0, 0);
}

// ---------------------------------------------------------------------------
// Fused prep: blocks [0,136) build R (8 replicas x 4352, zeros where d
// outside [0,4096)); [136,2184) convert E; [2184,2696) convert W.
// ---------------------------------------------------------------------------
__global__ void prep_kernel(const float* __restrict__ E, const float* __restrict__ W,
                            bf16_t* __restrict__ Eb, bf16_t* __restrict__ Wb,
                            bf16_t* __restrict__ R) {
    const int b = blockIdx.x;
    if (b < 136) {                       // 136*256 = 34816 = 8*4352 exact
        int idx = b * 256 + threadIdx.x;
        int s = idx / R_STRIDE;
        int x = idx - s * R_STRIDE;
        int d = R_O0 + s - x;
        float v = 0.0f;
        if (d >= 0 && d < L_SER)
            v = powf((d == 0) ? 1e-8f : ((float)d * (1.0f / (float)L_SER) + 1e-8f), 0.2f);
        R[idx] = (bf16_t)v;
    } else if (b < 136 + 2048) {         // E: 2048*256*8 = 4194304 elems exact
        int idx = (b - 136) * 256 + threadIdx.x;
        const f32x4* s = (const f32x4*)E;
        f32x4 v0 = s[idx * 2], v1 = s[idx * 2 + 1];
        bf16x8 o;
        o[0] = (bf16_t)v0[0]; o[1] = (bf16_t)v0[1]; o[2] = (bf16_t)v0[2]; o[3] = (bf16_t)v0[3];
        o[4] = (bf16_t)v1[0]; o[5] = (bf16_t)v1[1]; o[6] = (bf16_t)v1[2]; o[7] = (bf16_t)v1[3];
        ((bf16x8*)Eb)[idx] = o;
    } else {                             // W: 512*256*8 = 1048576 elems exact
        int idx = (b - 2184) * 256 + threadIdx.x;
        const f32x4* s = (const f32x4*)W;
        f32x4 v0 = s[idx * 2], v1 = s[idx * 2 + 1];
        bf16x8 o;
        o[0] = (bf16_t)v0[0]; o[1] = (bf16_t)v0[1]; o[2] = (bf16_t)v0[2]; o[3] = (bf16_t)v0[3];
        o[4] = (bf16_t)v1[0]; o[5] = (bf16_t)v1[1]; o[6] = (bf16_t)v1[2]; o[7] = (bf16_t)v1[3];
        ((bf16x8*)Wb)[idx] = o;
    }
}

// ---------------------------------------------------------------------------
// Shared lane machinery.
// ---------------------------------------------------------------------------
#define GA_LANES()                                                           \
    const int tid  = threadIdx.x;                                            \
    const int wave = tid >> 6;                                               \
    const int lane = tid & 63;                                               \
    const int quad = lane >> 4;                                              \
    const int ln   = lane & 15;                                              \
    const int wm   = wave >> 1;                                              \
    const int wn   = wave & 1;                                               \
    const int lrow = lane >> 3;                                              \
    const int lch  = (lane & 7) ^ lrow;                                      \
    const int rsw   = ln & 7;                                                \
    const int coff0 = ((quad ^ rsw)) * 8;                                    \
    const int coff1 = (((4 + quad) ^ rsw)) * 8;

// ---------------------------------------------------------------------------
// gemm_a: BM=128, BN=128, BK=128. 512 blocks (2/CU); pair (bid,bid+256)
// shares a CU -> 16-17 double-steps per CU. B-LDS [2][128][128] (64 KB),
// swizzle slot=(kk*4+quad)^(row&7); A = compressed window [2][8][248] (8 KB).
// (R12-verified.)
// ---------------------------------------------------------------------------
#define GA2_STAGE(SBOFS, WOFS)                                               \
    _Pragma("unroll")                                                        \
    for (int c = 0; c < 8; ++c) {                                            \
        glds16(pB[c], &sB[(SBOFS) + (c * 16 + wave * 4) * 128]);             \
        pB[c] += 128;                                                        \
    }                                                                        \
    glds16(pRwin, &sW[(WOFS) + wave * 512]);                                 \
    pRwin += 128;

#define GA2_COMPUTE(SBOFS, WOFS)                                             \
    _Pragma("unroll")                                                        \
    for (int kk = 0; kk < 4; ++kk) {                                         \
        const int co = (((kk * 4 + quad) ^ rsw)) * 8;                        \
        bf16x8 afr[4], bfr[4];                                               \
        _Pragma("unroll")                                                    \
        for (int tm = 0; tm < 4; ++tm)                                       \
            afr[tm] = *(const bf16x8*)&sW[(WOFS) + awbase + (kk * 32 + quad * 8 - 16 * tm)]; \
        _Pragma("unroll")                                                    \
        for (int tn = 0; tn < 4; ++tn)                                       \
            bfr[tn] = *(const bf16x8*)&sB[(SBOFS) + (wn * 64 + tn * 16 + ln) * 128 + co]; \
        _Pragma("unroll")                                                    \
        for (int tm = 0; tm < 4; ++tm)                                       \
            _Pragma("unroll")                                                \
            for (int tn = 0; tn < 4; ++tn)                                   \
                acc[tm][tn] = __builtin_amdgcn_mfma_f32_16x16x32_bf16(afr[tm], bfr[tn], acc[tm][tn], 0, 0, 0); \
    }

__global__ __launch_bounds__(256, 2) void gemm_a_kernel(const bf16_t* __restrict__ R,
                                                        const bf16_t* __restrict__ Eb,
                                                        bf16_t* __restrict__ T0,
                                                        bf16_t* __restrict__ T1) {
    __shared__ __align__(16) bf16_t sB[2 * 128 * 128];  // 64 KB (B tiles)
    __shared__ __align__(16) bf16_t sW[2 * 2048];       // 8 KB (A windows [8][248]+junk)

    const int bid = blockIdx.x;
    int I, nb, h;
    if (bid < 256) { I = bid >> 3;                nb = bid & 7;         h = 0; }
    else           { I = 31 - ((bid - 256) >> 3); nb = (bid - 256) & 7; h = 1; }
    const int i0 = I * 128;
    const int n0 = nb * 128;
    const int c0 = h ? ((I + 2) & ~1) : 0;
    const int nsteps2 = h ? ((2 * (I + 1) - c0) >> 1) : ((I + 2) >> 1);
    const int j0b = c0 * 64;
    bf16_t* __restrict__ Tout = h ? T1 : T0;

    GA_LANES()

    const int awbase = (ln & 7) * 248 + 120 - 64 * wm - 8 * (ln >> 3);

    f32x4 acc[4][4];
#pragma unroll
    for (int a = 0; a < 4; ++a)
#pragma unroll
        for (int b = 0; b < 4; ++b) acc[a][b] = (f32x4){0, 0, 0, 0};

    if (nsteps2 > 0) {
        int wrow = tid / 31;
        int wchk = tid - wrow * 31;
        if (tid >= 248) { wrow = 7; wchk = 30; }
        const bf16_t* pRwin = R + (size_t)wrow * R_STRIDE + (R_O0 - i0 + j0b - 120 + wchk * 8);

        const int r4  = lane >> 4;
        const int sch = (lane & 15) ^ (((wave & 1) * 4 + r4) & 7);
        const bf16_t* pB[8];
#pragma unroll
        for (int c = 0; c < 8; ++c)
            pB[c] = Eb + (size_t)(n0 + c * 16 + wave * 4 + r4) * L_SER + j0b + sch * 8;

        GA2_STAGE(0, 0)                              // step 0 -> buf0
        for (int s = 0;; s += 2) {
            __syncthreads();                         // drains buf0 stage
            if (s + 1 < nsteps2) { GA2_STAGE(128 * 128, 2048) }
            GA2_COMPUTE(0, 0)
            if (s + 1 >= nsteps2) break;
            __syncthreads();                         // drains buf1 stage
            if (s + 2 < nsteps2) { GA2_STAGE(0, 0) }
            GA2_COMPUTE(128 * 128, 2048)
            if (s + 2 >= nsteps2) break;
        }
    }

    // C/D: col = ln, row = quad*4 + r (m89-verified). Written even when
    // nsteps2==0 (I=0,h=1): zero acc -> defined T1.
#pragma unroll
    for (int tm = 0; tm < 4; ++tm) {
        int row_base = i0 + wm * 64 + tm * 16 + quad * 4;
#pragma unroll
        for (int tn = 0; tn < 4; ++tn) {
            int col = n0 + wn * 64 + tn * 16 + ln;
#pragma unroll
            for (int r = 0; r < 4; ++r)
                Tout[(size_t)(row_base + r) * DEMB + col] = (bf16_t)acc[tm][tn][r];
        }
    }
}

// ---------------------------------------------------------------------------
// gemm_b: BM=64, BN=128, BK=128, K=1024 -> 8 steps. 512 blocks (2/CU).
// A dual-stream in LDS [2][128][128] (rows 0..63 = T0 tile, 64..127 = T1),
// staged with R12's proven 8-glds16 pattern; W fragments in REGISTERS
// (wb0/wb1, 16 x bf16x8 each, static indexing), prefetched one step ahead
// from L2 (XCD-local 256 KB panel). Per wave per kk: 4 afr ds_reads + 16
// MFMA from register bfr.
// ---------------------------------------------------------------------------
#define GB2_STAGE_A(SBOFS)                                                   \
    _Pragma("unroll")                                                        \
    for (int c = 0; c < 8; ++c) {                                            \
        glds16(pA[c], &sA[(SBOFS) + (c * 16 + wave * 4) * 128]);             \
        pA[c] += 128;                                                        \
    }

#define GB2_WLOAD(WB)                                                        \
    _Pragma("unroll")                                                        \
    for (int kk = 0; kk < 4; ++kk)                                           \
        _Pragma("unroll")                                                    \
        for (int tn = 0; tn < 4; ++tn)                                       \
            WB[kk * 4 + tn] = *(const bf16x8*)(pW[tn] + kk * 32 + quad * 8); \
    _Pragma("unroll")                                                        \
    for (int tn = 0; tn < 4; ++tn) pW[tn] += 128;

#define GB2_COMPUTE(SBOFS, WB)                                               \
    _Pragma("unroll")                                                        \
    for (int kk = 0; kk < 4; ++kk) {                                         \
        const int co = (((kk * 4 + quad) ^ rsw)) * 8;                        \
        bf16x8 afr[4];                                                       \
        _Pragma("unroll")                                                    \
        for (int c = 0; c < 4; ++c)                                          \
            afr[c] = *(const bf16x8*)&sA[(SBOFS) + (((c >> 1) * 64) + wm * 32 + (c & 1) * 16 + ln) * 128 + co]; \
        _Pragma("unroll")                                                    \
        for (int t = 0; t < 2; ++t)                                          \
            _Pragma("unroll")                                                \
            for (int tn = 0; tn < 4; ++tn)                                   \
                acc[t][tn] = __builtin_amdgcn_mfma_f32_16x16x32_bf16(afr[t], WB[kk * 4 + tn], acc[t][tn], 0, 0, 0); \
        _Pragma("unroll")                                                    \
        for (int t = 0; t < 2; ++t)                                          \
            _Pragma("unroll")                                                \
            for (int tn = 0; tn < 4; ++tn)                                   \
                acc[t][tn] = __builtin_amdgcn_mfma_f32_16x16x32_bf16(afr[2 + t], WB[kk * 4 + tn], acc[t][tn], 0, 0, 0); \
    }

__global__ __launch_bounds__(256, 2) void gemm_b_kernel(const bf16_t* __restrict__ T0,
                                                        const bf16_t* __restrict__ T1,
                                                        const bf16_t* __restrict__ Wb,
                                                        float* __restrict__ out) {
    __shared__ __align__(16) bf16_t sA[2 * 128 * 128];   // 64 KB

    const int bid = blockIdx.x;
    const int ib = bid >> 3;        // 0..63
    const int nb = bid & 7;
    const int i0 = ib * 64;
    const int n0 = nb * 128;

    GA_LANES()

    f32x4 acc[2][4];
#pragma unroll
    for (int a = 0; a < 2; ++a)
#pragma unroll
        for (int b = 0; b < 4; ++b) acc[a][b] = (f32x4){0, 0, 0, 0};

    const int nsteps = DEMB / 128;  // 8 (even)

    // A staging rows: c<4 -> T0 rows c*16+wave*4+r4; c>=4 -> T1 rows
    // (c-4)*16+wave*4+r4. LDS row = c*16+wave*4+r4; row&7 = (wave&1)*4+r4.
    const int r4  = lane >> 4;
    const int sch = (lane & 15) ^ (((wave & 1) * 4 + r4) & 7);
    const bf16_t* pA[8];
#pragma unroll
    for (int c = 0; c < 8; ++c) {
        const bf16_t* base = (c < 4) ? T0 : T1;
        int rr = (c & 3) * 16 + wave * 4 + r4;
        pA[c] = base + (size_t)(i0 + rr) * DEMB + sch * 8;
    }
    // W row pointers: row = n0 + wn*64 + tn*16 + ln
    const bf16_t* pW[4];
#pragma unroll
    for (int tn = 0; tn < 4; ++tn)
        pW[tn] = Wb + (size_t)(n0 + wn * 64 + tn * 16 + ln) * DEMB;

    bf16x8 wb0[16], wb1[16];

    GB2_WLOAD(wb0)                               // step 0 W -> regs
    GB2_STAGE_A(0)                               // step 0 A -> buf0
    for (int s = 0;; s += 2) {
        __syncthreads();                         // A(s) visible
        if (s + 1 < nsteps) { GB2_STAGE_A(128 * 128) GB2_WLOAD(wb1) }
        GB2_COMPUTE(0, wb0)
        if (s + 1 >= nsteps) break;
        __syncthreads();                         // A(s+1) visible
        if (s + 2 < nsteps) { GB2_STAGE_A(0) GB2_WLOAD(wb0) }
        GB2_COMPUTE(128 * 128, wb1)
        if (s + 2 >= nsteps) break;
    }

#pragma unroll
    for (int t = 0; t < 2; ++t) {
        int row_base = i0 + wm * 32 + t * 16 + quad * 4;
#pragma unroll
        for (int tn = 0; tn < 4; ++tn) {
            int col = n0 + wn * 64 + tn * 16 + ln;
#pragma unroll
            for (int r = 0; r < 4; ++r)
                out[(size_t)(row_base + r) * DV + col] = acc[t][tn][r];
        }
    }
}

// ---------------------------------------------------------------------------
extern "C" void kernel_launch(void* const* d_in, const int* in_sizes, int n_in,
                              void* d_out, int out_size, void* d_ws, size_t ws_size,
                              hipStream_t stream) {
    const float* E = (const float*)d_in[0];   // (1024, 4096) f32
    const float* W = (const float*)d_in[1];   // (1024, 1024) f32
    float* out = (float*)d_out;               // (4096, 1024) f32

    char* ws = (char*)d_ws;
    bf16_t* Eb = (bf16_t*)(ws);                               // 8 MB
    bf16_t* T0 = (bf16_t*)(ws + (size_t)8  * 1024 * 1024);    // 8 MB
    bf16_t* T1 = (bf16_t*)(ws + (size_t)16 * 1024 * 1024);    // 8 MB
    bf16_t* Wb = (bf16_t*)(ws + (size_t)24 * 1024 * 1024);    // 2 MB
    bf16_t* R  = (bf16_t*)(ws + (size_t)26 * 1024 * 1024);    // 68 KB

    prep_kernel<<<2696, 256, 0, stream>>>(E, W, Eb, Wb, R);
    gemm_a_kernel<<<512, 256, 0, stream>>>(R, Eb, T0, T1);
    gemm_b_kernel<<<512, 256, 0, stream>>>(T0, T1, Wb, out);
}

// Round 15
// 121.815 us; speedup vs baseline: 1.1068x; 1.1068x over previous
//
#include <hip/hip_runtime.h>
#include <hip/hip_bf16.h>
#include <cstdint>
#include <cstddef>

// out = (A2 @ E^T) @ W^T, A2[i,j] = a[i-j] lower-tri Toeplitz,
//   a[d] = (d/4096 + 1e-8)^0.2, a[0] = 1e-8^0.2
// gemm_a: T[i,e] = sum_{j<=i} a[i-j] * E[e,j]  (tri, split-j -> T0 + T1)
// gemm_b: out[i,v] = sum_e T0[i,e]*W[v,e] + sum_e T1[i,e]*W[v,e]
// Round 21: R14 regressed +17us -- W-in-VGPR loads are a 16-line gather
// (R9's mechanism; L1 throughput, prefetch can't fix). Confirmed rule:
// per-lane-row fragment feeds must transit LDS. Reverted to exact R12
// (117.49 best) + ONE safe change: SWAPPED-OPERAND MFMA in both GEMMs.
// A/B fragment lane layouts are symmetric (both read rows via ln), so
// mfma(Efrag, Rfrag) / mfma(Wfrag, Tfrag) transposes the acc layout:
// each lane's 4 acc elems = 4 CONSECUTIVE output columns -> gemm_a T-write
// packs to 8B bf16x4 stores (4x fewer VMEM ops on 8MB), gemm_b out-write
// becomes one f32x4 16B store per fragment (4x fewer ops on 16MB).
// K-loops/staging/swizzles byte-identical to R12.

#define L_SER 4096
#define DEMB  1024
#define DV    1024

#define R_STRIDE 4352   // shift-replica stride of reversed a; 16B-aligned; zero-padded tail
#define R_O0     4096

typedef __bf16 bf16_t;
typedef __attribute__((ext_vector_type(8))) __bf16 bf16x8;
typedef __attribute__((ext_vector_type(4))) __bf16 bf16x4;
typedef __attribute__((ext_vector_type(4))) float f32x4;

// direct global->LDS async copy, 16B per lane (dest = uniform base + lane*16)
__device__ __forceinline__ void glds16(const bf16_t* g, bf16_t* l) {
    __builtin_amdgcn_global_load_lds(
        (const __attribute__((address_space(1))) unsigned int*)(const void*)g,
        (__attribute__((address_space(3))) unsigned int*)(void*)l,
        16, 0, 0);
}

// ---------------------------------------------------------------------------
// Fused prep: blocks [0,136) build R (8 replicas x 4352, zeros where d
// outside [0,4096)); [136,2184) convert E; [2184,2696) convert W.
// ---------------------------------------------------------------------------
__global__ void prep_kernel(const float* __restrict__ E, const float* __restrict__ W,
                            bf16_t* __restrict__ Eb, bf16_t* __restrict__ Wb,
                            bf16_t* __restrict__ R) {
    const int b = blockIdx.x;
    if (b < 136) {                       // 136*256 = 34816 = 8*4352 exact
        int idx = b * 256 + threadIdx.x;
        int s = idx / R_STRIDE;
        int x = idx - s * R_STRIDE;
        int d = R_O0 + s - x;
        float v = 0.0f;
        if (d >= 0 && d < L_SER)
            v = powf((d == 0) ? 1e-8f : ((float)d * (1.0f / (float)L_SER) + 1e-8f), 0.2f);
        R[idx] = (bf16_t)v;
    } else if (b < 136 + 2048) {         // E: 2048*256*8 = 4194304 elems exact
        int idx = (b - 136) * 256 + threadIdx.x;
        const f32x4* s = (const f32x4*)E;
        f32x4 v0 = s[idx * 2], v1 = s[idx * 2 + 1];
        bf16x8 o;
        o[0] = (bf16_t)v0[0]; o[1] = (bf16_t)v0[1]; o[2] = (bf16_t)v0[2]; o[3] = (bf16_t)v0[3];
        o[4] = (bf16_t)v1[0]; o[5] = (bf16_t)v1[1]; o[6] = (bf16_t)v1[2]; o[7] = (bf16_t)v1[3];
        ((bf16x8*)Eb)[idx] = o;
    } else {                             // W: 512*256*8 = 1048576 elems exact
        int idx = (b - 2184) * 256 + threadIdx.x;
        const f32x4* s = (const f32x4*)W;
        f32x4 v0 = s[idx * 2], v1 = s[idx * 2 + 1];
        bf16x8 o;
        o[0] = (bf16_t)v0[0]; o[1] = (bf16_t)v0[1]; o[2] = (bf16_t)v0[2]; o[3] = (bf16_t)v0[3];
        o[4] = (bf16_t)v1[0]; o[5] = (bf16_t)v1[1]; o[6] = (bf16_t)v1[2]; o[7] = (bf16_t)v1[3];
        ((bf16x8*)Wb)[idx] = o;
    }
}

// ---------------------------------------------------------------------------
// Shared lane machinery.
// ---------------------------------------------------------------------------
#define GA_LANES()                                                           \
    const int tid  = threadIdx.x;                                            \
    const int wave = tid >> 6;                                               \
    const int lane = tid & 63;                                               \
    const int quad = lane >> 4;                                              \
    const int ln   = lane & 15;                                              \
    const int wm   = wave >> 1;                                              \
    const int wn   = wave & 1;                                               \
    const int lrow = lane >> 3;                                              \
    const int lch  = (lane & 7) ^ lrow;                                      \
    const int rsw   = ln & 7;                                                \
    const int coff0 = ((quad ^ rsw)) * 8;                                    \
    const int coff1 = (((4 + quad) ^ rsw)) * 8;

// ---------------------------------------------------------------------------
// gemm_a: BM=128, BN=128, BK=128. 512 blocks (2/CU); pair (bid,bid+256)
// shares a CU -> 16-17 double-steps per CU. B-LDS [2][128][128] (64 KB),
// swizzle slot=(kk*4+quad)^(row&7); A = compressed window [2][8][248] (8 KB).
// (R12-verified staging.) MFMA operand-SWAPPED: D[m=e][n=i] so each lane's
// 4 acc elems = 4 consecutive e -> bf16x4 T-stores.
// ---------------------------------------------------------------------------
#define GA2_STAGE(SBOFS, WOFS)                                               \
    _Pragma("unroll")                                                        \
    for (int c = 0; c < 8; ++c) {                                            \
        glds16(pB[c], &sB[(SBOFS) + (c * 16 + wave * 4) * 128]);             \
        pB[c] += 128;                                                        \
    }                                                                        \
    glds16(pRwin, &sW[(WOFS) + wave * 512]);                                 \
    pRwin += 128;

#define GA2_COMPUTE(SBOFS, WOFS)                                             \
    _Pragma("unroll")                                                        \
    for (int kk = 0; kk < 4; ++kk) {                                         \
        const int co = (((kk * 4 + quad) ^ rsw)) * 8;                        \
        bf16x8 afr[4], bfr[4];                                               \
        _Pragma("unroll")                                                    \
        for (int ti = 0; ti < 4; ++ti)                                       \
            afr[ti] = *(const bf16x8*)&sW[(WOFS) + awbase + (kk * 32 + quad * 8 - 16 * ti)]; \
        _Pragma("unroll")                                                    \
        for (int te = 0; te < 4; ++te)                                       \
            bfr[te] = *(const bf16x8*)&sB[(SBOFS) + (wn * 64 + te * 16 + ln) * 128 + co]; \
        _Pragma("unroll")                                                    \
        for (int te = 0; te < 4; ++te)                                       \
            _Pragma("unroll")                                                \
            for (int ti = 0; ti < 4; ++ti)                                   \
                acc[te][ti] = __builtin_amdgcn_mfma_f32_16x16x32_bf16(bfr[te], afr[ti], acc[te][ti], 0, 0, 0); \
    }

__global__ __launch_bounds__(256, 2) void gemm_a_kernel(const bf16_t* __restrict__ R,
                                                        const bf16_t* __restrict__ Eb,
                                                        bf16_t* __restrict__ T0,
                                                        bf16_t* __restrict__ T1) {
    __shared__ __align__(16) bf16_t sB[2 * 128 * 128];  // 64 KB (B tiles)
    __shared__ __align__(16) bf16_t sW[2 * 2048];       // 8 KB (A windows [8][248]+junk)

    const int bid = blockIdx.x;
    int I, nb, h;
    if (bid < 256) { I = bid >> 3;                nb = bid & 7;         h = 0; }
    else           { I = 31 - ((bid - 256) >> 3); nb = (bid - 256) & 7; h = 1; }
    const int i0 = I * 128;
    const int n0 = nb * 128;
    const int c0 = h ? ((I + 2) & ~1) : 0;
    const int nsteps2 = h ? ((2 * (I + 1) - c0) >> 1) : ((I + 2) >> 1);
    const int j0b = c0 * 64;
    bf16_t* __restrict__ Tout = h ? T1 : T0;

    GA_LANES()

    const int awbase = (ln & 7) * 248 + 120 - 64 * wm - 8 * (ln >> 3);

    f32x4 acc[4][4];
#pragma unroll
    for (int a = 0; a < 4; ++a)
#pragma unroll
        for (int b = 0; b < 4; ++b) acc[a][b] = (f32x4){0, 0, 0, 0};

    if (nsteps2 > 0) {
        int wrow = tid / 31;
        int wchk = tid - wrow * 31;
        if (tid >= 248) { wrow = 7; wchk = 30; }
        const bf16_t* pRwin = R + (size_t)wrow * R_STRIDE + (R_O0 - i0 + j0b - 120 + wchk * 8);

        const int r4  = lane >> 4;
        const int sch = (lane & 15) ^ (((wave & 1) * 4 + r4) & 7);
        const bf16_t* pB[8];
#pragma unroll
        for (int c = 0; c < 8; ++c)
            pB[c] = Eb + (size_t)(n0 + c * 16 + wave * 4 + r4) * L_SER + j0b + sch * 8;

        GA2_STAGE(0, 0)                              // step 0 -> buf0
        for (int s = 0;; s += 2) {
            __syncthreads();                         // drains buf0 stage
            if (s + 1 < nsteps2) { GA2_STAGE(128 * 128, 2048) }
            GA2_COMPUTE(0, 0)
            if (s + 1 >= nsteps2) break;
            __syncthreads();                         // drains buf1 stage
            if (s + 2 < nsteps2) { GA2_STAGE(0, 0) }
            GA2_COMPUTE(128 * 128, 2048)
            if (s + 2 >= nsteps2) break;
        }
    }

    // Swapped C/D: m(rows quad*4+r) = e-dim, n(col ln) = i-dim.
    // e = n0 + wn*64 + te*16 + quad*4 + r; i = i0 + wm*64 + ti*16 + ln.
    // 4 r-values -> 4 consecutive e -> one 8B bf16x4 store.
    // Written even when nsteps2==0 (I=0,h=1): zero acc -> defined T1.
#pragma unroll
    for (int te = 0; te < 4; ++te) {
        int e_base = n0 + wn * 64 + te * 16 + quad * 4;
#pragma unroll
        for (int ti = 0; ti < 4; ++ti) {
            int i_out = i0 + wm * 64 + ti * 16 + ln;
            bf16x4 v;
#pragma unroll
            for (int r = 0; r < 4; ++r) v[r] = (bf16_t)acc[te][ti][r];
            *(bf16x4*)&Tout[(size_t)i_out * DEMB + e_base] = v;
        }
    }
}

// ---------------------------------------------------------------------------
// gemm_b: BM=64, BN=128, BK=64, K=1024, dual A-stream (T0,T1). 512 blocks
// (2/CU). A-LDS rows 0..63 = T0 tile, rows 64..127 = T1 tile; W in LDS.
// (R12-verified staging.) MFMA operand-SWAPPED: D[m=v][n=i] -> each lane's
// acc f32x4 = 4 consecutive v -> one 16B f32x4 out-store per fragment.
// ---------------------------------------------------------------------------
#define GB_STAGE(SBOFS)                                                      \
    _Pragma("unroll")                                                        \
    for (int c = 0; c < 4; ++c) {                                            \
        glds16(pA[c], &sA[(SBOFS) + (c * 32 + wave * 8) * 64]);              \
        glds16(pW[c], &sBB[(SBOFS) + (c * 32 + wave * 8) * 64]);             \
        pA[c] += 64; pW[c] += 64;                                            \
    }

#define GB_COMPUTE(SBOFS)                                                    \
    _Pragma("unroll")                                                        \
    for (int kk = 0; kk < 2; ++kk) {                                         \
        const int co = kk ? coff1 : coff0;                                   \
        bf16x8 afr[4], bfr[4];                                               \
        _Pragma("unroll")                                                    \
        for (int c = 0; c < 4; ++c)                                          \
            afr[c] = *(const bf16x8*)&sA[(SBOFS) + (((c >> 1) * 64) + wm * 32 + (c & 1) * 16 + ln) * 64 + co]; \
        _Pragma("unroll")                                                    \
        for (int tv = 0; tv < 4; ++tv)                                       \
            bfr[tv] = *(const bf16x8*)&sBB[(SBOFS) + (wn * 64 + tv * 16 + ln) * 64 + co]; \
        _Pragma("unroll")                                                    \
        for (int tv = 0; tv < 4; ++tv)                                       \
            _Pragma("unroll")                                                \
            for (int ti = 0; ti < 2; ++ti)                                   \
                acc[tv][ti] = __builtin_amdgcn_mfma_f32_16x16x32_bf16(bfr[tv], afr[ti], acc[tv][ti], 0, 0, 0); \
        _Pragma("unroll")                                                    \
        for (int tv = 0; tv < 4; ++tv)                                       \
            _Pragma("unroll")                                                \
            for (int ti = 0; ti < 2; ++ti)                                   \
                acc[tv][ti] = __builtin_amdgcn_mfma_f32_16x16x32_bf16(bfr[tv], afr[2 + ti], acc[tv][ti], 0, 0, 0); \
    }

__global__ __launch_bounds__(256, 2) void gemm_b_kernel(const bf16_t* __restrict__ T0,
                                                        const bf16_t* __restrict__ T1,
                                                        const bf16_t* __restrict__ Wb,
                                                        float* __restrict__ out) {
    __shared__ __align__(16) bf16_t sA[2 * 128 * 64];    // 32 KB
    __shared__ __align__(16) bf16_t sBB[2 * 128 * 64];   // 32 KB

    const int bid = blockIdx.x;
    const int ib = bid >> 3;        // 0..63
    const int nb = bid & 7;
    const int i0 = ib * 64;
    const int n0 = nb * 128;

    GA_LANES()

    f32x4 acc[4][2];
#pragma unroll
    for (int a = 0; a < 4; ++a)
#pragma unroll
        for (int b = 0; b < 2; ++b) acc[a][b] = (f32x4){0, 0, 0, 0};

    const int nsteps = DEMB / 64;   // 16 (even)

    // A staging: c=0,1 -> T0 rows (c&1)*32+..., LDS rows 0..63;
    //            c=2,3 -> T1 rows (c&1)*32+..., LDS rows 64..127.
    const bf16_t* pA[4];
    const bf16_t* pW[4];
#pragma unroll
    for (int c = 0; c < 4; ++c) {
        const bf16_t* base = (c < 2) ? T0 : T1;
        int rr = (c & 1) * 32 + wave * 8 + lrow;
        pA[c] = base + (size_t)(i0 + rr) * DEMB + lch * 8;
        pW[c] = Wb + (size_t)(n0 + c * 32 + wave * 8 + lrow) * DEMB + lch * 8;
    }

    GB_STAGE(0)                                  // step 0 -> buf0
    for (int s = 0;; s += 2) {
        __syncthreads();                         // drains buf0 stage
        if (s + 1 < nsteps) { GB_STAGE(128 * 64) }
        GB_COMPUTE(0)
        if (s + 1 >= nsteps) break;
        __syncthreads();                         // drains buf1 stage
        if (s + 2 < nsteps) { GB_STAGE(0) }
        GB_COMPUTE(128 * 64)
        if (s + 2 >= nsteps) break;
    }

    // Swapped C/D: v = n0 + wn*64 + tv*16 + quad*4 + r; i = i0 + wm*32 +
    // ti*16 + ln. acc f32x4 = 4 consecutive v -> one 16B store.
#pragma unroll
    for (int tv = 0; tv < 4; ++tv) {
        int v_base = n0 + wn * 64 + tv * 16 + quad * 4;
#pragma unroll
        for (int ti = 0; ti < 2; ++ti) {
            int i_out = i0 + wm * 32 + ti * 16 + ln;
            *(f32x4*)&out[(size_t)i_out * DV + v_base] = acc[tv][ti];
        }
    }
}

// ---------------------------------------------------------------------------
extern "C" void kernel_launch(void* const* d_in, const int* in_sizes, int n_in,
                              void* d_out, int out_size, void* d_ws, size_t ws_size,
                              hipStream_t stream) {
    const float* E = (const float*)d_in[0];   // (1024, 4096) f32
    const float* W = (const float*)d_in[1];   // (1024, 1024) f32
    float* out = (float*)d_out;               // (4096, 1024) f32

    char* ws = (char*)d_ws;
    bf16_t* Eb = (bf16_t*)(ws);                               // 8 MB
    bf16_t* T0 = (bf16_t*)(ws + (size_t)8  * 1024 * 1024);    // 8 MB
    bf16_t* T1 = (bf16_t*)(ws + (size_t)16 * 1024 * 1024);    // 8 MB
    bf16_t* Wb = (bf16_t*)(ws + (size_t)24 * 1024 * 1024);    // 2 MB
    bf16_t* R  = (bf16_t*)(ws + (size_t)26 * 1024 * 1024);    // 68 KB

    prep_kernel<<<2696, 256, 0, stream>>>(E, W, Eb, Wb, R);
    gemm_a_kernel<<<512, 256, 0, stream>>>(R, Eb, T0, T1);
    gemm_b_kernel<<<512, 256, 0, stream>>>(T0, T1, Wb, out);
}